// Round 9
// baseline (1193.550 us; speedup 1.0000x reference)
//
#include <hip/hip_runtime.h>
#include <cmath>

typedef __attribute__((ext_vector_type(8))) short short8v;
typedef __attribute__((ext_vector_type(4))) short short4v;
typedef __attribute__((ext_vector_type(4))) float f32x4;

__device__ inline short f2bf(float f) {
  union { float f; unsigned u; } a; a.f = f;
  unsigned r = a.u + 0x7FFF + ((a.u >> 16) & 1);   // RTN-even
  return (short)(r >> 16);
}
__device__ inline float bf2f(short b) {
  union { unsigned u; float f; } a; a.u = ((unsigned)(unsigned short)b) << 16;
  return a.f;
}

// ---------------------------------------------------------------------------
// Graph build, bucketed:
//  A) bin_edges: scatter (d,s) pairs into 256-node dst-buckets (sequential
//     writes per bucket -> no 64B-line write amplification).
//  B) scan bucket counts -> bucket edge offsets (== col offsets).
//  C) bucket_csr: per bucket (1 block): LDS histogram -> deg/dinv, LDS scan
//     -> rs, LDS cursors -> col scatter into a contiguous 16KB region.
// ---------------------------------------------------------------------------
__global__ void bin_edges_kernel(const int* __restrict__ src, const int* __restrict__ dst,
                                 int* __restrict__ bktCur, uint2* __restrict__ pairBuf,
                                 int e, int cap) {
  int i = blockIdx.x * blockDim.x + threadIdx.x;
  int stride = gridDim.x * blockDim.x;
  for (; i < e; i += stride) {
    int d = dst[i], s = src[i];
    int b = d >> 8;
    int p = atomicAdd(&bktCur[b], 1);
    pairBuf[(size_t)b * cap + p] = make_uint2((unsigned)d, (unsigned)s);
  }
}

__global__ void scan_bkt_kernel(const int* __restrict__ bktCur, int* __restrict__ bktOff,
                                int nb) {
  __shared__ int s[512];
  int t = threadIdx.x;
  int v = (t < nb) ? bktCur[t] : 0;
  s[t] = v;
  for (int off = 1; off < 512; off <<= 1) {
    __syncthreads();
    int add = (t >= off) ? s[t - off] : 0;
    __syncthreads();
    s[t] += add;
  }
  if (t < nb) bktOff[t] = s[t] - v;   // exclusive
}

__global__ __launch_bounds__(256) void bucket_csr_kernel(
    const uint2* __restrict__ pairBuf, const int* __restrict__ bktCur,
    const int* __restrict__ bktOff, int* __restrict__ deg, int* __restrict__ rs,
    float* __restrict__ dinv, int* __restrict__ col, int n, int cap) {
  __shared__ int hist[256];
  __shared__ int loff[256];
  __shared__ int cur[256];
  int b = blockIdx.x;
  int base = b << 8;
  int m = n - base; if (m > 256) m = 256;
  int t = threadIdx.x;
  hist[t] = 0;
  __syncthreads();
  int cnt = bktCur[b];
  const uint2* pb = pairBuf + (size_t)b * cap;
  for (int j = t; j < cnt; j += 256)
    atomicAdd(&hist[pb[j].x - base], 1);
  __syncthreads();
  int own = hist[t];
  loff[t] = own;
  for (int off = 1; off < 256; off <<= 1) {
    __syncthreads();
    int add = (t >= off) ? loff[t - off] : 0;
    __syncthreads();
    loff[t] += add;
  }
  __syncthreads();
  int excl = loff[t] - own;
  int bo = bktOff[b];
  if (t < m) {
    deg[base + t] = own;
    rs[base + t] = bo + excl;
    dinv[base + t] = rsqrtf((float)own + 1.0f);
  }
  __syncthreads();
  hist[t] = excl;     // reuse as per-node exclusive offset
  cur[t] = 0;
  __syncthreads();
  for (int j = t; j < cnt; j += 256) {
    int d = pb[j].x - base;
    int q = atomicAdd(&cur[d], 1);
    col[bo + hist[d] + q] = (int)pb[j].y;
  }
}

// ---------------------------------------------------------------------------
// Weight converts
// ---------------------------------------------------------------------------
__global__ void convert_wt_kernel(const float* __restrict__ W, short* __restrict__ Wt,
                                  int K, int N) {
  int i = blockIdx.x * blockDim.x + threadIdx.x;
  if (i < K * N) {
    int k = i / N, nn = i - k * N;
    Wt[nn * K + k] = f2bf(W[i]);
  }
}

// W2 [256][40] f32 -> W2t [64][256] bf16, zero-padded cols 40..63
__global__ void convert_w2t_kernel(const float* __restrict__ W2, short* __restrict__ W2t) {
  int i = blockIdx.x * blockDim.x + threadIdx.x;
  if (i < 64 * 256) {
    int c = i >> 8, k = i & 255;
    W2t[i] = (c < 40) ? f2bf(W2[k * 40 + c]) : (short)0;
  }
}

// ---------------------------------------------------------------------------
// MFMA GEMM with int8 quantizing epilogue, 2-phase pipelined staging.
// BM=64 x BN=256 (wave per 64-col slab), BK=64, XOR-swizzled LDS (41KB).
//   G8[r,c] = rint(val*127/rowmax);  gscale[r] = dinv[r]*rowmax/127
// ---------------------------------------------------------------------------
template <int K, bool AF32>
__global__ __launch_bounds__(256, 2) void gemm_mfma_kernel(
    const void* __restrict__ Aptr, const short* __restrict__ Wt,
    const float* __restrict__ dinv, char* __restrict__ G8,
    float* __restrict__ gscale, int n) {
  __shared__ short As[64 * 64];    // 8 KB
  __shared__ short Bs[256 * 64];   // 32 KB
  __shared__ float rmax[4][64];    // 1 KB
  int tid = threadIdx.x;
  int lane = tid & 63, wn = tid >> 6;
  int l15 = lane & 15, lh = lane >> 4;
  int rowBase = blockIdx.x * 64;

  f32x4 acc[4][4];
#pragma unroll
  for (int mi = 0; mi < 4; mi++)
#pragma unroll
    for (int ni = 0; ni < 4; ni++) acc[mi][ni] = (f32x4){0.f, 0.f, 0.f, 0.f};

  short8v aS[2], bS[8];

  auto LOAD = [&](int kt) {
#pragma unroll
    for (int i = 0; i < 2; i++) {
      int s = tid + i * 256;
      int r = s >> 3, u = s & 7;
      int gr = rowBase + r; if (gr >= n) gr = n - 1;
      if constexpr (AF32) {
        const float* ap = (const float*)Aptr + (size_t)gr * K + kt + u * 8;
        float4 f0 = *(const float4*)ap;
        float4 f1 = *(const float4*)(ap + 4);
        short8v v;
        v[0] = f2bf(f0.x); v[1] = f2bf(f0.y); v[2] = f2bf(f0.z); v[3] = f2bf(f0.w);
        v[4] = f2bf(f1.x); v[5] = f2bf(f1.y); v[6] = f2bf(f1.z); v[7] = f2bf(f1.w);
        aS[i] = v;
      } else {
        aS[i] = *(const short8v*)((const short*)Aptr + (size_t)gr * K + kt + u * 8);
      }
    }
#pragma unroll
    for (int i = 0; i < 8; i++) {
      int s = tid + i * 256;
      int r = s >> 3, u = s & 7;
      bS[i] = *(const short8v*)(Wt + (size_t)r * K + kt + u * 8);
    }
  };

  auto STORE = [&]() {
#pragma unroll
    for (int i = 0; i < 2; i++) {
      int s = tid + i * 256;
      int r = s >> 3, u = s & 7;
      *(short8v*)&As[r * 64 + ((u ^ (r & 7)) << 3)] = aS[i];
    }
#pragma unroll
    for (int i = 0; i < 8; i++) {
      int s = tid + i * 256;
      int r = s >> 3, u = s & 7;
      *(short8v*)&Bs[r * 64 + ((u ^ (r & 7)) << 3)] = bS[i];
    }
  };

  auto COMPUTE = [&]() {
#pragma unroll
    for (int kk = 0; kk < 2; kk++) {
      int u = kk * 4 + lh;
      short8v af[4], bf[4];
#pragma unroll
      for (int mi = 0; mi < 4; mi++) {
        int r = mi * 16 + l15;
        af[mi] = *(const short8v*)&As[r * 64 + ((u ^ (r & 7)) << 3)];
      }
#pragma unroll
      for (int ni = 0; ni < 4; ni++) {
        int r = wn * 64 + ni * 16 + l15;
        bf[ni] = *(const short8v*)&Bs[r * 64 + ((u ^ (r & 7)) << 3)];
      }
#pragma unroll
      for (int mi = 0; mi < 4; mi++)
#pragma unroll
        for (int ni = 0; ni < 4; ni++)
          acc[mi][ni] = __builtin_amdgcn_mfma_f32_16x16x32_bf16(
              af[mi], bf[ni], acc[mi][ni], 0, 0, 0);
    }
  };

  LOAD(0);
  STORE();
  __syncthreads();
  for (int kt = 64; kt < K; kt += 64) {
    LOAD(kt);
    COMPUTE();
    __syncthreads();
    STORE();
    __syncthreads();
  }
  COMPUTE();

  // ---- quantizing epilogue ----
#pragma unroll
  for (int mi = 0; mi < 4; mi++) {
#pragma unroll
    for (int j = 0; j < 4; j++) {
      float mx = 0.f;
#pragma unroll
      for (int ni = 0; ni < 4; ni++) mx = fmaxf(mx, fabsf(acc[mi][ni][j]));
      for (int off = 1; off < 16; off <<= 1)
        mx = fmaxf(mx, __shfl_xor(mx, off, 64));
      if (l15 == 0) rmax[wn][mi * 16 + lh * 4 + j] = mx;
    }
  }
  __syncthreads();
#pragma unroll
  for (int mi = 0; mi < 4; mi++) {
#pragma unroll
    for (int j = 0; j < 4; j++) {
      int r = mi * 16 + lh * 4 + j;
      int gr = rowBase + r;
      if (gr < n) {
        float cmax = fmaxf(fmaxf(rmax[0][r], rmax[1][r]),
                           fmaxf(rmax[2][r], rmax[3][r]));
        float inv = (cmax > 0.f) ? 127.f / cmax : 0.f;
        if (wn == 0 && l15 == 0)
          gscale[gr] = dinv[gr] * cmax * (1.f / 127.f);
#pragma unroll
        for (int ni = 0; ni < 4; ni++) {
          int gc = wn * 64 + ni * 16 + l15;
          int q = (int)rintf(acc[mi][ni][j] * inv);
          G8[(size_t)gr * 256 + gc] = (char)q;
        }
      }
    }
  }
}

// ---------------------------------------------------------------------------
// Final MFMA GEMM: G2b[r, 0:40] = bf16( (Hb[r,:256] @ W2[:256,0:40]) * dinv[r] )
// ---------------------------------------------------------------------------
__global__ __launch_bounds__(256, 3) void gemm_mfma40_kernel(
    const short* __restrict__ Hb, const short* __restrict__ W2t,
    const float* __restrict__ dinv, short* __restrict__ G2b, int n) {
  __shared__ short As[256 * 64];   // 32 KB
  __shared__ short Bs[64 * 64];    // 8 KB
  int tid = threadIdx.x;
  int lane = tid & 63, wid = tid >> 6;
  int l15 = lane & 15, lh = lane >> 4;
  int rowBase = blockIdx.x * 256;

  f32x4 acc[4][4];
#pragma unroll
  for (int mi = 0; mi < 4; mi++)
#pragma unroll
    for (int ni = 0; ni < 4; ni++) acc[mi][ni] = (f32x4){0.f, 0.f, 0.f, 0.f};

  for (int kt = 0; kt < 256; kt += 64) {
#pragma unroll
    for (int i = 0; i < 8; i++) {
      int s = tid + i * 256;
      int r = s >> 3, u = s & 7;
      int gr = rowBase + r; if (gr >= n) gr = n - 1;
      short8v v = *(const short8v*)(Hb + (size_t)gr * 256 + kt + u * 8);
      *(short8v*)&As[r * 64 + ((u ^ (r & 7)) << 3)] = v;
    }
#pragma unroll
    for (int i = 0; i < 2; i++) {
      int s = tid + i * 256;
      int r = s >> 3, u = s & 7;
      short8v v = *(const short8v*)(W2t + (size_t)r * 256 + kt + u * 8);
      *(short8v*)&Bs[r * 64 + ((u ^ (r & 7)) << 3)] = v;
    }
    __syncthreads();
#pragma unroll
    for (int kk = 0; kk < 2; kk++) {
      int u = kk * 4 + lh;
      short8v af[4], bf[4];
#pragma unroll
      for (int mi = 0; mi < 4; mi++) {
        int r = wid * 64 + mi * 16 + l15;
        af[mi] = *(const short8v*)&As[r * 64 + ((u ^ (r & 7)) << 3)];
      }
#pragma unroll
      for (int ni = 0; ni < 4; ni++) {
        int r = ni * 16 + l15;
        bf[ni] = *(const short8v*)&Bs[r * 64 + ((u ^ (r & 7)) << 3)];
      }
#pragma unroll
      for (int mi = 0; mi < 4; mi++)
#pragma unroll
        for (int ni = 0; ni < 4; ni++)
          acc[mi][ni] = __builtin_amdgcn_mfma_f32_16x16x32_bf16(
              af[mi], bf[ni], acc[mi][ni], 0, 0, 0);
    }
    __syncthreads();
  }

#pragma unroll
  for (int mi = 0; mi < 4; mi++) {
#pragma unroll
    for (int j = 0; j < 4; j++) {
      int gr = rowBase + wid * 64 + mi * 16 + lh * 4 + j;
      if (gr < n) {
        float sc = dinv[gr];
#pragma unroll
        for (int ni = 0; ni < 4; ni++) {
          int gc = ni * 16 + l15;
          if (gc < 40) G2b[(size_t)gr * 40 + gc] = f2bf(acc[mi][ni][j] * sc);
        }
      }
    }
  }
}

// ---------------------------------------------------------------------------
// Aggregate 256-dim from int8 G + per-row scale, f32 accumulate.
// ---------------------------------------------------------------------------
__device__ inline void dq_acc(int w, float s, float& a0, float& a1,
                              float& a2, float& a3) {
  a0 += (float)(signed char)(w & 0xff) * s;
  a1 += (float)(signed char)((w >> 8) & 0xff) * s;
  a2 += (float)(signed char)((w >> 16) & 0xff) * s;
  a3 += (float)(signed char)(w >> 24) * s;
}

template <int RELU, int WF32>
__global__ __launch_bounds__(256) void aggregate_i8_kernel(
    const char* __restrict__ G8, const float* __restrict__ gsc,
    const int* __restrict__ col, const int* __restrict__ rs,
    const int* __restrict__ deg, const float* __restrict__ dinv,
    const float* __restrict__ bias, short* __restrict__ Hb,
    float* __restrict__ Hf, int n) {
  int wid = threadIdx.x >> 6;
  int lane = threadIdx.x & 63;
  int v = blockIdx.x * 4 + wid;
  if (v >= n) return;
  float a0 = 0.f, a1 = 0.f, a2 = 0.f, a3 = 0.f;
  {
    int w = *(const int*)(G8 + (size_t)v * 256 + lane * 4);
    dq_acc(w, gsc[v], a0, a1, a2, a3);
  }
  int base = rs[v], cnt = deg[v];
  for (int i0 = 0; i0 < cnt; i0 += 64) {
    int rem = cnt - i0; if (rem > 64) rem = 64;
    int ci = col[base + i0 + (lane < rem ? lane : 0)];
    int i = 0;
    for (; i + 8 <= rem; i += 8) {
      int u0 = __shfl(ci, i + 0), u1 = __shfl(ci, i + 1);
      int u2 = __shfl(ci, i + 2), u3 = __shfl(ci, i + 3);
      int u4 = __shfl(ci, i + 4), u5 = __shfl(ci, i + 5);
      int u6 = __shfl(ci, i + 6), u7 = __shfl(ci, i + 7);
      int w0 = *(const int*)(G8 + (size_t)u0 * 256 + lane * 4);
      int w1 = *(const int*)(G8 + (size_t)u1 * 256 + lane * 4);
      int w2 = *(const int*)(G8 + (size_t)u2 * 256 + lane * 4);
      int w3 = *(const int*)(G8 + (size_t)u3 * 256 + lane * 4);
      int w4 = *(const int*)(G8 + (size_t)u4 * 256 + lane * 4);
      int w5 = *(const int*)(G8 + (size_t)u5 * 256 + lane * 4);
      int w6 = *(const int*)(G8 + (size_t)u6 * 256 + lane * 4);
      int w7 = *(const int*)(G8 + (size_t)u7 * 256 + lane * 4);
      float s0 = gsc[u0], s1 = gsc[u1], s2 = gsc[u2], s3 = gsc[u3];
      float s4 = gsc[u4], s5 = gsc[u5], s6 = gsc[u6], s7 = gsc[u7];
      dq_acc(w0, s0, a0, a1, a2, a3);
      dq_acc(w1, s1, a0, a1, a2, a3);
      dq_acc(w2, s2, a0, a1, a2, a3);
      dq_acc(w3, s3, a0, a1, a2, a3);
      dq_acc(w4, s4, a0, a1, a2, a3);
      dq_acc(w5, s5, a0, a1, a2, a3);
      dq_acc(w6, s6, a0, a1, a2, a3);
      dq_acc(w7, s7, a0, a1, a2, a3);
    }
    for (; i < rem; i++) {
      int u = __shfl(ci, i);
      int w = *(const int*)(G8 + (size_t)u * 256 + lane * 4);
      dq_acc(w, gsc[u], a0, a1, a2, a3);
    }
  }
  float s = dinv[v];
  float4 b4 = ((const float4*)bias)[lane];
  float o0 = a0 * s + b4.x, o1 = a1 * s + b4.y, o2 = a2 * s + b4.z, o3 = a3 * s + b4.w;
  if (RELU) {
    o0 = fmaxf(o0, 0.f); o1 = fmaxf(o1, 0.f);
    o2 = fmaxf(o2, 0.f); o3 = fmaxf(o3, 0.f);
  }
  short4v ob; ob[0] = f2bf(o0); ob[1] = f2bf(o1); ob[2] = f2bf(o2); ob[3] = f2bf(o3);
  *(short4v*)(Hb + (size_t)v * 256 + lane * 4) = ob;
  if (WF32) {
    float4 of; of.x = o0; of.y = o1; of.z = o2; of.w = o3;
    *(float4*)(Hf + (size_t)v * 256 + lane * 4) = of;
  }
}

// ---------------------------------------------------------------------------
// Aggregate 40-dim (bf16 rows) + bias + log_softmax.
// ---------------------------------------------------------------------------
__global__ __launch_bounds__(256) void agg40_lsm_kernel(
    const short* __restrict__ G2b, const int* __restrict__ col,
    const int* __restrict__ rs, const int* __restrict__ deg,
    const float* __restrict__ dinv, const float* __restrict__ b2,
    float* __restrict__ out, int n) {
  int wid = threadIdx.x >> 6;
  int lane = threadIdx.x & 63;
  int v = blockIdx.x * 4 + wid;
  if (v >= n) return;
  bool act = lane < 40;
  int ln = act ? lane : 0;
  float acc = act ? bf2f(G2b[(size_t)v * 40 + lane]) : 0.f;
  int base = rs[v], cnt = deg[v];
  for (int i0 = 0; i0 < cnt; i0 += 64) {
    int rem = cnt - i0; if (rem > 64) rem = 64;
    int ci = col[base + i0 + (lane < rem ? lane : 0)];
    int i = 0;
    for (; i + 4 <= rem; i += 4) {
      int u0 = __shfl(ci, i + 0), u1 = __shfl(ci, i + 1);
      int u2 = __shfl(ci, i + 2), u3 = __shfl(ci, i + 3);
      float x0 = bf2f(G2b[(size_t)u0 * 40 + ln]);
      float x1 = bf2f(G2b[(size_t)u1 * 40 + ln]);
      float x2 = bf2f(G2b[(size_t)u2 * 40 + ln]);
      float x3 = bf2f(G2b[(size_t)u3 * 40 + ln]);
      acc += x0 + x1 + x2 + x3;
    }
    for (; i < rem; i++) {
      int u = __shfl(ci, i);
      acc += bf2f(G2b[(size_t)u * 40 + ln]);
    }
  }
  float val;
  if (act) val = acc * dinv[v] + b2[lane];
  else val = -INFINITY;
  float m = val;
  for (int off = 32; off; off >>= 1) m = fmaxf(m, __shfl_xor(m, off, 64));
  float e = act ? expf(val - m) : 0.f;
  float ssum = e;
  for (int off = 32; off; off >>= 1) ssum += __shfl_xor(ssum, off, 64);
  if (act) out[(size_t)v * 40 + lane] = val - m - logf(ssum);
}

// ---------------------------------------------------------------------------

static inline size_t alignup(size_t x) { return (x + 255) & ~(size_t)255; }

extern "C" void kernel_launch(void* const* d_in, const int* in_sizes, int n_in,
                              void* d_out, int out_size, void* d_ws, size_t ws_size,
                              hipStream_t stream) {
  const float* x  = (const float*)d_in[0];
  const int*   ei = (const int*)d_in[1];
  const float* W1 = (const float*)d_in[2];
  const float* b1 = (const float*)d_in[3];
  const float* Wi = (const float*)d_in[4];
  const float* bi = (const float*)d_in[5];
  const float* W2 = (const float*)d_in[6];
  const float* b2 = (const float*)d_in[7];

  const int in_d = 512, mid_d = 256, out_d = 40;
  int n = in_sizes[0] / in_d;       // 100000
  int E = in_sizes[1] / 2;          // 1600000
  const int* src = ei;
  const int* dst = ei + E;

  float* out_lsm = (float*)d_out;                        // n*40
  float* emb     = (float*)d_out + (size_t)n * out_d;    // n*256

  int NB = (n + 255) >> 8;                       // 391 buckets of 256 nodes
  int cap = ((E / NB) * 3) / 2 + 1024;           // ~7162 per-bucket capacity

  char* w = (char*)d_ws;
  float* dinv  = (float*)w;  w += alignup((size_t)n * 4);
  int* deg     = (int*)w;    w += alignup((size_t)n * 4);
  int* rs      = (int*)w;    w += alignup((size_t)n * 4);
  int* colidx  = (int*)w;    w += alignup((size_t)E * 4);
  int* bktCur  = (int*)w;    w += alignup((size_t)NB * 4);
  int* bktOff  = (int*)w;    w += alignup((size_t)NB * 4);
  uint2* pairBuf = (uint2*)w; w += alignup((size_t)NB * cap * 8);   // ~22 MB
  short* W1t   = (short*)w;  w += alignup((size_t)mid_d * in_d * 2);
  short* Wit   = (short*)w;  w += alignup((size_t)mid_d * mid_d * 2);
  short* W2t   = (short*)w;  w += alignup((size_t)64 * mid_d * 2);
  char* G8     = (char*)w;   w += alignup((size_t)n * mid_d);       // int8 g
  float* gsc   = (float*)w;  w += alignup((size_t)n * 4);           // row scales
  short* Hb    = (short*)w;  w += alignup((size_t)n * mid_d * 2);   // bf16 h
  short* G2b   = (short*)G8;  // alias: G8 dead when final gemm runs

  // --- bucketed graph build ---
  hipMemsetAsync(bktCur, 0, (size_t)NB * 4, stream);
  bin_edges_kernel<<<2048, 256, 0, stream>>>(src, dst, bktCur, pairBuf, E, cap);
  scan_bkt_kernel<<<1, 512, 0, stream>>>(bktCur, bktOff, NB);
  bucket_csr_kernel<<<NB, 256, 0, stream>>>(pairBuf, bktCur, bktOff,
                                            deg, rs, dinv, colidx, n, cap);

  convert_wt_kernel<<<(in_d * mid_d + 255) / 256, 256, 0, stream>>>(W1, W1t, in_d, mid_d);
  convert_wt_kernel<<<(mid_d * mid_d + 255) / 256, 256, 0, stream>>>(Wi, Wit, mid_d, mid_d);
  convert_w2t_kernel<<<(64 * mid_d + 255) / 256, 256, 0, stream>>>(W2, W2t);

  int ggrid = (n + 63) / 64;       // 1563
  int agg_grid = (n + 3) / 4;

  // conv1
  gemm_mfma_kernel<512, true><<<ggrid, 256, 0, stream>>>(x, W1t, dinv, G8, gsc, n);
  aggregate_i8_kernel<0, 0><<<agg_grid, 256, 0, stream>>>(
      G8, gsc, colidx, rs, deg, dinv, b1, Hb, nullptr, n);
  // conv2..3
  for (int l = 0; l < 2; l++) {
    gemm_mfma_kernel<256, false><<<ggrid, 256, 0, stream>>>(Hb, Wit, dinv, G8, gsc, n);
    aggregate_i8_kernel<1, 0><<<agg_grid, 256, 0, stream>>>(
        G8, gsc, colidx, rs, deg, dinv, bi, Hb, nullptr, n);
  }
  // conv4 (+ f32 emb)
  gemm_mfma_kernel<256, false><<<ggrid, 256, 0, stream>>>(Hb, Wit, dinv, G8, gsc, n);
  aggregate_i8_kernel<1, 1><<<agg_grid, 256, 0, stream>>>(
      G8, gsc, colidx, rs, deg, dinv, bi, Hb, emb, n);

  // conv5: MFMA projection (bf16 out) + lsm aggregate
  gemm_mfma40_kernel<<<(n + 255) / 256, 256, 0, stream>>>(Hb, W2t, dinv, G2b, n);
  agg40_lsm_kernel<<<agg_grid, 256, 0, stream>>>(G2b, colidx, rs, deg, dinv, b2, out_lsm, n);
}

// Round 10
// 668.387 us; speedup vs baseline: 1.7857x; 1.7857x over previous
//
#include <hip/hip_runtime.h>
#include <cmath>

typedef __attribute__((ext_vector_type(8))) short short8v;
typedef __attribute__((ext_vector_type(4))) short short4v;
typedef __attribute__((ext_vector_type(4))) float f32x4;

__device__ inline short f2bf(float f) {
  union { float f; unsigned u; } a; a.f = f;
  unsigned r = a.u + 0x7FFF + ((a.u >> 16) & 1);   // RTN-even
  return (short)(r >> 16);
}
__device__ inline float bf2f(short b) {
  union { unsigned u; float f; } a; a.u = ((unsigned)(unsigned short)b) << 16;
  return a.f;
}

// ---------------------------------------------------------------------------
// Graph build, bucketed with privatized cursors:
//  A) bin_edges2: per-block LDS histogram over 256-node dst-buckets; ONE
//     global atomic per (block,bucket) reserves a contiguous run; LDS-cursor
//     scatter writes ~128B runs (no line amplification, no hot cursors).
//  B) scan bucket counts -> bucket edge offsets (== col offsets).
//  C) bucket_csr: per bucket (1 block): LDS histogram -> deg/dinv, LDS scan
//     -> rs, LDS cursors -> col scatter into a contiguous 16KB region.
// ---------------------------------------------------------------------------
__global__ __launch_bounds__(256) void bin_edges2_kernel(
    const int* __restrict__ src, const int* __restrict__ dst,
    int* __restrict__ bktCur, uint2* __restrict__ pairBuf,
    int e, int cap, int nbk) {
  __shared__ int hist[512];
  __shared__ int lbase[512];
  __shared__ int cur[512];
  int t = threadIdx.x;
  for (int i = t; i < nbk; i += 256) hist[i] = 0;
  __syncthreads();
  int chunk = (e + gridDim.x - 1) / gridDim.x;
  int s0 = blockIdx.x * chunk;
  int s1 = s0 + chunk; if (s1 > e) s1 = e;
  for (int j = s0 + t; j < s1; j += 256)
    atomicAdd(&hist[((unsigned)dst[j]) >> 8], 1);
  __syncthreads();
  for (int i = t; i < nbk; i += 256) {
    int c = hist[i];
    lbase[i] = c ? atomicAdd(&bktCur[i], c) : 0;
    cur[i] = 0;
  }
  __syncthreads();
  for (int j = s0 + t; j < s1; j += 256) {
    int d = dst[j], s = src[j];
    int b = ((unsigned)d) >> 8;
    int q = atomicAdd(&cur[b], 1);
    pairBuf[(size_t)b * cap + lbase[b] + q] = make_uint2((unsigned)d, (unsigned)s);
  }
}

__global__ void scan_bkt_kernel(const int* __restrict__ bktCur, int* __restrict__ bktOff,
                                int nb) {
  __shared__ int s[512];
  int t = threadIdx.x;
  int v = (t < nb) ? bktCur[t] : 0;
  s[t] = v;
  for (int off = 1; off < 512; off <<= 1) {
    __syncthreads();
    int add = (t >= off) ? s[t - off] : 0;
    __syncthreads();
    s[t] += add;
  }
  if (t < nb) bktOff[t] = s[t] - v;   // exclusive
}

__global__ __launch_bounds__(256) void bucket_csr_kernel(
    const uint2* __restrict__ pairBuf, const int* __restrict__ bktCur,
    const int* __restrict__ bktOff, int* __restrict__ deg, int* __restrict__ rs,
    float* __restrict__ dinv, int* __restrict__ col, int n, int cap) {
  __shared__ int hist[256];
  __shared__ int loff[256];
  __shared__ int cur[256];
  int b = blockIdx.x;
  int base = b << 8;
  int m = n - base; if (m > 256) m = 256;
  int t = threadIdx.x;
  hist[t] = 0;
  __syncthreads();
  int cnt = bktCur[b];
  const uint2* pb = pairBuf + (size_t)b * cap;
  for (int j = t; j < cnt; j += 256)
    atomicAdd(&hist[pb[j].x - base], 1);
  __syncthreads();
  int own = hist[t];
  loff[t] = own;
  for (int off = 1; off < 256; off <<= 1) {
    __syncthreads();
    int add = (t >= off) ? loff[t - off] : 0;
    __syncthreads();
    loff[t] += add;
  }
  __syncthreads();
  int excl = loff[t] - own;
  int bo = bktOff[b];
  if (t < m) {
    deg[base + t] = own;
    rs[base + t] = bo + excl;
    dinv[base + t] = rsqrtf((float)own + 1.0f);
  }
  __syncthreads();
  hist[t] = excl;     // reuse as per-node exclusive offset
  cur[t] = 0;
  __syncthreads();
  for (int j = t; j < cnt; j += 256) {
    int d = pb[j].x - base;
    int q = atomicAdd(&cur[d], 1);
    col[bo + hist[d] + q] = (int)pb[j].y;
  }
}

// ---------------------------------------------------------------------------
// Weight converts
// ---------------------------------------------------------------------------
__global__ void convert_wt_kernel(const float* __restrict__ W, short* __restrict__ Wt,
                                  int K, int N) {
  int i = blockIdx.x * blockDim.x + threadIdx.x;
  if (i < K * N) {
    int k = i / N, nn = i - k * N;
    Wt[nn * K + k] = f2bf(W[i]);
  }
}

// W2 [256][40] f32 -> W2t [64][256] bf16, zero-padded cols 40..63
__global__ void convert_w2t_kernel(const float* __restrict__ W2, short* __restrict__ W2t) {
  int i = blockIdx.x * blockDim.x + threadIdx.x;
  if (i < 64 * 256) {
    int c = i >> 8, k = i & 255;
    W2t[i] = (c < 40) ? f2bf(W2[k * 40 + c]) : (short)0;
  }
}

// ---------------------------------------------------------------------------
// MFMA GEMM with int8 quantizing epilogue, 2-phase pipelined staging.
// BM=64 x BN=256 (wave per 64-col slab), BK=64, XOR-swizzled LDS (41KB).
//   G8[r,c] = rint(val*127/rowmax);  gscale[r] = dinv[r]*rowmax/127
// ---------------------------------------------------------------------------
template <int K, bool AF32>
__global__ __launch_bounds__(256, 2) void gemm_mfma_kernel(
    const void* __restrict__ Aptr, const short* __restrict__ Wt,
    const float* __restrict__ dinv, char* __restrict__ G8,
    float* __restrict__ gscale, int n) {
  __shared__ short As[64 * 64];    // 8 KB
  __shared__ short Bs[256 * 64];   // 32 KB
  __shared__ float rmax[4][64];    // 1 KB
  int tid = threadIdx.x;
  int lane = tid & 63, wn = tid >> 6;
  int l15 = lane & 15, lh = lane >> 4;
  int rowBase = blockIdx.x * 64;

  f32x4 acc[4][4];
#pragma unroll
  for (int mi = 0; mi < 4; mi++)
#pragma unroll
    for (int ni = 0; ni < 4; ni++) acc[mi][ni] = (f32x4){0.f, 0.f, 0.f, 0.f};

  short8v aS[2], bS[8];

  auto LOAD = [&](int kt) {
#pragma unroll
    for (int i = 0; i < 2; i++) {
      int s = tid + i * 256;
      int r = s >> 3, u = s & 7;
      int gr = rowBase + r; if (gr >= n) gr = n - 1;
      if constexpr (AF32) {
        const float* ap = (const float*)Aptr + (size_t)gr * K + kt + u * 8;
        float4 f0 = *(const float4*)ap;
        float4 f1 = *(const float4*)(ap + 4);
        short8v v;
        v[0] = f2bf(f0.x); v[1] = f2bf(f0.y); v[2] = f2bf(f0.z); v[3] = f2bf(f0.w);
        v[4] = f2bf(f1.x); v[5] = f2bf(f1.y); v[6] = f2bf(f1.z); v[7] = f2bf(f1.w);
        aS[i] = v;
      } else {
        aS[i] = *(const short8v*)((const short*)Aptr + (size_t)gr * K + kt + u * 8);
      }
    }
#pragma unroll
    for (int i = 0; i < 8; i++) {
      int s = tid + i * 256;
      int r = s >> 3, u = s & 7;
      bS[i] = *(const short8v*)(Wt + (size_t)r * K + kt + u * 8);
    }
  };

  auto STORE = [&]() {
#pragma unroll
    for (int i = 0; i < 2; i++) {
      int s = tid + i * 256;
      int r = s >> 3, u = s & 7;
      *(short8v*)&As[r * 64 + ((u ^ (r & 7)) << 3)] = aS[i];
    }
#pragma unroll
    for (int i = 0; i < 8; i++) {
      int s = tid + i * 256;
      int r = s >> 3, u = s & 7;
      *(short8v*)&Bs[r * 64 + ((u ^ (r & 7)) << 3)] = bS[i];
    }
  };

  auto COMPUTE = [&]() {
#pragma unroll
    for (int kk = 0; kk < 2; kk++) {
      int u = kk * 4 + lh;
      short8v af[4], bf[4];
#pragma unroll
      for (int mi = 0; mi < 4; mi++) {
        int r = mi * 16 + l15;
        af[mi] = *(const short8v*)&As[r * 64 + ((u ^ (r & 7)) << 3)];
      }
#pragma unroll
      for (int ni = 0; ni < 4; ni++) {
        int r = wn * 64 + ni * 16 + l15;
        bf[ni] = *(const short8v*)&Bs[r * 64 + ((u ^ (r & 7)) << 3)];
      }
#pragma unroll
      for (int mi = 0; mi < 4; mi++)
#pragma unroll
        for (int ni = 0; ni < 4; ni++)
          acc[mi][ni] = __builtin_amdgcn_mfma_f32_16x16x32_bf16(
              af[mi], bf[ni], acc[mi][ni], 0, 0, 0);
    }
  };

  LOAD(0);
  STORE();
  __syncthreads();
  for (int kt = 64; kt < K; kt += 64) {
    LOAD(kt);
    COMPUTE();
    __syncthreads();
    STORE();
    __syncthreads();
  }
  COMPUTE();

  // ---- quantizing epilogue ----
#pragma unroll
  for (int mi = 0; mi < 4; mi++) {
#pragma unroll
    for (int j = 0; j < 4; j++) {
      float mx = 0.f;
#pragma unroll
      for (int ni = 0; ni < 4; ni++) mx = fmaxf(mx, fabsf(acc[mi][ni][j]));
      for (int off = 1; off < 16; off <<= 1)
        mx = fmaxf(mx, __shfl_xor(mx, off, 64));
      if (l15 == 0) rmax[wn][mi * 16 + lh * 4 + j] = mx;
    }
  }
  __syncthreads();
#pragma unroll
  for (int mi = 0; mi < 4; mi++) {
#pragma unroll
    for (int j = 0; j < 4; j++) {
      int r = mi * 16 + lh * 4 + j;
      int gr = rowBase + r;
      if (gr < n) {
        float cmax = fmaxf(fmaxf(rmax[0][r], rmax[1][r]),
                           fmaxf(rmax[2][r], rmax[3][r]));
        float inv = (cmax > 0.f) ? 127.f / cmax : 0.f;
        if (wn == 0 && l15 == 0)
          gscale[gr] = dinv[gr] * cmax * (1.f / 127.f);
#pragma unroll
        for (int ni = 0; ni < 4; ni++) {
          int gc = wn * 64 + ni * 16 + l15;
          int q = (int)rintf(acc[mi][ni][j] * inv);
          G8[(size_t)gr * 256 + gc] = (char)q;
        }
      }
    }
  }
}

// ---------------------------------------------------------------------------
// Final MFMA GEMM: G2b[r, 0:40] = bf16( (Hb[r,:256] @ W2[:256,0:40]) * dinv[r] )
// ---------------------------------------------------------------------------
__global__ __launch_bounds__(256, 3) void gemm_mfma40_kernel(
    const short* __restrict__ Hb, const short* __restrict__ W2t,
    const float* __restrict__ dinv, short* __restrict__ G2b, int n) {
  __shared__ short As[256 * 64];   // 32 KB
  __shared__ short Bs[64 * 64];    // 8 KB
  int tid = threadIdx.x;
  int lane = tid & 63, wid = tid >> 6;
  int l15 = lane & 15, lh = lane >> 4;
  int rowBase = blockIdx.x * 256;

  f32x4 acc[4][4];
#pragma unroll
  for (int mi = 0; mi < 4; mi++)
#pragma unroll
    for (int ni = 0; ni < 4; ni++) acc[mi][ni] = (f32x4){0.f, 0.f, 0.f, 0.f};

  for (int kt = 0; kt < 256; kt += 64) {
#pragma unroll
    for (int i = 0; i < 8; i++) {
      int s = tid + i * 256;
      int r = s >> 3, u = s & 7;
      int gr = rowBase + r; if (gr >= n) gr = n - 1;
      short8v v = *(const short8v*)(Hb + (size_t)gr * 256 + kt + u * 8);
      *(short8v*)&As[r * 64 + ((u ^ (r & 7)) << 3)] = v;
    }
#pragma unroll
    for (int i = 0; i < 2; i++) {
      int s = tid + i * 256;
      int r = s >> 3, u = s & 7;
      short8v v = *(const short8v*)(W2t + (size_t)r * 256 + kt + u * 8);
      *(short8v*)&Bs[r * 64 + ((u ^ (r & 7)) << 3)] = v;
    }
    __syncthreads();
#pragma unroll
    for (int kk = 0; kk < 2; kk++) {
      int u = kk * 4 + lh;
      short8v af[4], bf[4];
#pragma unroll
      for (int mi = 0; mi < 4; mi++) {
        int r = wid * 64 + mi * 16 + l15;
        af[mi] = *(const short8v*)&As[r * 64 + ((u ^ (r & 7)) << 3)];
      }
#pragma unroll
      for (int ni = 0; ni < 4; ni++) {
        int r = ni * 16 + l15;
        bf[ni] = *(const short8v*)&Bs[r * 64 + ((u ^ (r & 7)) << 3)];
      }
#pragma unroll
      for (int mi = 0; mi < 4; mi++)
#pragma unroll
        for (int ni = 0; ni < 4; ni++)
          acc[mi][ni] = __builtin_amdgcn_mfma_f32_16x16x32_bf16(
              af[mi], bf[ni], acc[mi][ni], 0, 0, 0);
    }
    __syncthreads();
  }

#pragma unroll
  for (int mi = 0; mi < 4; mi++) {
#pragma unroll
    for (int j = 0; j < 4; j++) {
      int gr = rowBase + wid * 64 + mi * 16 + lh * 4 + j;
      if (gr < n) {
        float sc = dinv[gr];
#pragma unroll
        for (int ni = 0; ni < 4; ni++) {
          int gc = ni * 16 + l15;
          if (gc < 40) G2b[(size_t)gr * 40 + gc] = f2bf(acc[mi][ni][j] * sc);
        }
      }
    }
  }
}

// ---------------------------------------------------------------------------
// Aggregate 256-dim from int8 G + per-row scale, f32 accumulate.
// ---------------------------------------------------------------------------
__device__ inline void dq_acc(int w, float s, float& a0, float& a1,
                              float& a2, float& a3) {
  a0 += (float)(signed char)(w & 0xff) * s;
  a1 += (float)(signed char)((w >> 8) & 0xff) * s;
  a2 += (float)(signed char)((w >> 16) & 0xff) * s;
  a3 += (float)(signed char)(w >> 24) * s;
}

template <int RELU, int WF32>
__global__ __launch_bounds__(256) void aggregate_i8_kernel(
    const char* __restrict__ G8, const float* __restrict__ gsc,
    const int* __restrict__ col, const int* __restrict__ rs,
    const int* __restrict__ deg, const float* __restrict__ dinv,
    const float* __restrict__ bias, short* __restrict__ Hb,
    float* __restrict__ Hf, int n) {
  int wid = threadIdx.x >> 6;
  int lane = threadIdx.x & 63;
  int v = blockIdx.x * 4 + wid;
  if (v >= n) return;
  float a0 = 0.f, a1 = 0.f, a2 = 0.f, a3 = 0.f;
  {
    int w = *(const int*)(G8 + (size_t)v * 256 + lane * 4);
    dq_acc(w, gsc[v], a0, a1, a2, a3);
  }
  int base = rs[v], cnt = deg[v];
  for (int i0 = 0; i0 < cnt; i0 += 64) {
    int rem = cnt - i0; if (rem > 64) rem = 64;
    int ci = col[base + i0 + (lane < rem ? lane : 0)];
    int i = 0;
    for (; i + 8 <= rem; i += 8) {
      int u0 = __shfl(ci, i + 0), u1 = __shfl(ci, i + 1);
      int u2 = __shfl(ci, i + 2), u3 = __shfl(ci, i + 3);
      int u4 = __shfl(ci, i + 4), u5 = __shfl(ci, i + 5);
      int u6 = __shfl(ci, i + 6), u7 = __shfl(ci, i + 7);
      int w0 = *(const int*)(G8 + (size_t)u0 * 256 + lane * 4);
      int w1 = *(const int*)(G8 + (size_t)u1 * 256 + lane * 4);
      int w2 = *(const int*)(G8 + (size_t)u2 * 256 + lane * 4);
      int w3 = *(const int*)(G8 + (size_t)u3 * 256 + lane * 4);
      int w4 = *(const int*)(G8 + (size_t)u4 * 256 + lane * 4);
      int w5 = *(const int*)(G8 + (size_t)u5 * 256 + lane * 4);
      int w6 = *(const int*)(G8 + (size_t)u6 * 256 + lane * 4);
      int w7 = *(const int*)(G8 + (size_t)u7 * 256 + lane * 4);
      float s0 = gsc[u0], s1 = gsc[u1], s2 = gsc[u2], s3 = gsc[u3];
      float s4 = gsc[u4], s5 = gsc[u5], s6 = gsc[u6], s7 = gsc[u7];
      dq_acc(w0, s0, a0, a1, a2, a3);
      dq_acc(w1, s1, a0, a1, a2, a3);
      dq_acc(w2, s2, a0, a1, a2, a3);
      dq_acc(w3, s3, a0, a1, a2, a3);
      dq_acc(w4, s4, a0, a1, a2, a3);
      dq_acc(w5, s5, a0, a1, a2, a3);
      dq_acc(w6, s6, a0, a1, a2, a3);
      dq_acc(w7, s7, a0, a1, a2, a3);
    }
    for (; i < rem; i++) {
      int u = __shfl(ci, i);
      int w = *(const int*)(G8 + (size_t)u * 256 + lane * 4);
      dq_acc(w, gsc[u], a0, a1, a2, a3);
    }
  }
  float s = dinv[v];
  float4 b4 = ((const float4*)bias)[lane];
  float o0 = a0 * s + b4.x, o1 = a1 * s + b4.y, o2 = a2 * s + b4.z, o3 = a3 * s + b4.w;
  if (RELU) {
    o0 = fmaxf(o0, 0.f); o1 = fmaxf(o1, 0.f);
    o2 = fmaxf(o2, 0.f); o3 = fmaxf(o3, 0.f);
  }
  short4v ob; ob[0] = f2bf(o0); ob[1] = f2bf(o1); ob[2] = f2bf(o2); ob[3] = f2bf(o3);
  *(short4v*)(Hb + (size_t)v * 256 + lane * 4) = ob;
  if (WF32) {
    float4 of; of.x = o0; of.y = o1; of.z = o2; of.w = o3;
    *(float4*)(Hf + (size_t)v * 256 + lane * 4) = of;
  }
}

// ---------------------------------------------------------------------------
// Aggregate 40-dim (bf16 rows) + bias + log_softmax.
// ---------------------------------------------------------------------------
__global__ __launch_bounds__(256) void agg40_lsm_kernel(
    const short* __restrict__ G2b, const int* __restrict__ col,
    const int* __restrict__ rs, const int* __restrict__ deg,
    const float* __restrict__ dinv, const float* __restrict__ b2,
    float* __restrict__ out, int n) {
  int wid = threadIdx.x >> 6;
  int lane = threadIdx.x & 63;
  int v = blockIdx.x * 4 + wid;
  if (v >= n) return;
  bool act = lane < 40;
  int ln = act ? lane : 0;
  float acc = act ? bf2f(G2b[(size_t)v * 40 + lane]) : 0.f;
  int base = rs[v], cnt = deg[v];
  for (int i0 = 0; i0 < cnt; i0 += 64) {
    int rem = cnt - i0; if (rem > 64) rem = 64;
    int ci = col[base + i0 + (lane < rem ? lane : 0)];
    int i = 0;
    for (; i + 4 <= rem; i += 4) {
      int u0 = __shfl(ci, i + 0), u1 = __shfl(ci, i + 1);
      int u2 = __shfl(ci, i + 2), u3 = __shfl(ci, i + 3);
      float x0 = bf2f(G2b[(size_t)u0 * 40 + ln]);
      float x1 = bf2f(G2b[(size_t)u1 * 40 + ln]);
      float x2 = bf2f(G2b[(size_t)u2 * 40 + ln]);
      float x3 = bf2f(G2b[(size_t)u3 * 40 + ln]);
      acc += x0 + x1 + x2 + x3;
    }
    for (; i < rem; i++) {
      int u = __shfl(ci, i);
      acc += bf2f(G2b[(size_t)u * 40 + ln]);
    }
  }
  float val;
  if (act) val = acc * dinv[v] + b2[lane];
  else val = -INFINITY;
  float m = val;
  for (int off = 32; off; off >>= 1) m = fmaxf(m, __shfl_xor(m, off, 64));
  float e = act ? expf(val - m) : 0.f;
  float ssum = e;
  for (int off = 32; off; off >>= 1) ssum += __shfl_xor(ssum, off, 64);
  if (act) out[(size_t)v * 40 + lane] = val - m - logf(ssum);
}

// ---------------------------------------------------------------------------

static inline size_t alignup(size_t x) { return (x + 255) & ~(size_t)255; }

extern "C" void kernel_launch(void* const* d_in, const int* in_sizes, int n_in,
                              void* d_out, int out_size, void* d_ws, size_t ws_size,
                              hipStream_t stream) {
  const float* x  = (const float*)d_in[0];
  const int*   ei = (const int*)d_in[1];
  const float* W1 = (const float*)d_in[2];
  const float* b1 = (const float*)d_in[3];
  const float* Wi = (const float*)d_in[4];
  const float* bi = (const float*)d_in[5];
  const float* W2 = (const float*)d_in[6];
  const float* b2 = (const float*)d_in[7];

  const int in_d = 512, mid_d = 256, out_d = 40;
  int n = in_sizes[0] / in_d;       // 100000
  int E = in_sizes[1] / 2;          // 1600000
  const int* src = ei;
  const int* dst = ei + E;

  float* out_lsm = (float*)d_out;                        // n*40
  float* emb     = (float*)d_out + (size_t)n * out_d;    // n*256

  int NB = (n + 255) >> 8;                       // 391 buckets of 256 nodes
  int cap = ((E / NB) * 3) / 2 + 1024;           // ~7162 per-bucket capacity

  char* w = (char*)d_ws;
  float* dinv  = (float*)w;  w += alignup((size_t)n * 4);
  int* deg     = (int*)w;    w += alignup((size_t)n * 4);
  int* rs      = (int*)w;    w += alignup((size_t)n * 4);
  int* colidx  = (int*)w;    w += alignup((size_t)E * 4);
  int* bktCur  = (int*)w;    w += alignup((size_t)NB * 4);
  int* bktOff  = (int*)w;    w += alignup((size_t)NB * 4);
  uint2* pairBuf = (uint2*)w; w += alignup((size_t)NB * cap * 8);   // ~22 MB
  short* W1t   = (short*)w;  w += alignup((size_t)mid_d * in_d * 2);
  short* Wit   = (short*)w;  w += alignup((size_t)mid_d * mid_d * 2);
  short* W2t   = (short*)w;  w += alignup((size_t)64 * mid_d * 2);
  char* G8     = (char*)w;   w += alignup((size_t)n * mid_d);       // int8 g
  float* gsc   = (float*)w;  w += alignup((size_t)n * 4);           // row scales
  short* Hb    = (short*)w;  w += alignup((size_t)n * mid_d * 2);   // bf16 h
  short* G2b   = (short*)G8;  // alias: G8 dead when final gemm runs

  // --- bucketed graph build (privatized cursors) ---
  hipMemsetAsync(bktCur, 0, (size_t)NB * 4, stream);
  bin_edges2_kernel<<<256, 256, 0, stream>>>(src, dst, bktCur, pairBuf, E, cap, NB);
  scan_bkt_kernel<<<1, 512, 0, stream>>>(bktCur, bktOff, NB);
  bucket_csr_kernel<<<NB, 256, 0, stream>>>(pairBuf, bktCur, bktOff,
                                            deg, rs, dinv, colidx, n, cap);

  convert_wt_kernel<<<(in_d * mid_d + 255) / 256, 256, 0, stream>>>(W1, W1t, in_d, mid_d);
  convert_wt_kernel<<<(mid_d * mid_d + 255) / 256, 256, 0, stream>>>(Wi, Wit, mid_d, mid_d);
  convert_w2t_kernel<<<(64 * mid_d + 255) / 256, 256, 0, stream>>>(W2, W2t);

  int ggrid = (n + 63) / 64;       // 1563
  int agg_grid = (n + 3) / 4;

  // conv1
  gemm_mfma_kernel<512, true><<<ggrid, 256, 0, stream>>>(x, W1t, dinv, G8, gsc, n);
  aggregate_i8_kernel<0, 0><<<agg_grid, 256, 0, stream>>>(
      G8, gsc, colidx, rs, deg, dinv, b1, Hb, nullptr, n);
  // conv2..3
  for (int l = 0; l < 2; l++) {
    gemm_mfma_kernel<256, false><<<ggrid, 256, 0, stream>>>(Hb, Wit, dinv, G8, gsc, n);
    aggregate_i8_kernel<1, 0><<<agg_grid, 256, 0, stream>>>(
        G8, gsc, colidx, rs, deg, dinv, bi, Hb, nullptr, n);
  }
  // conv4 (+ f32 emb)
  gemm_mfma_kernel<256, false><<<ggrid, 256, 0, stream>>>(Hb, Wit, dinv, G8, gsc, n);
  aggregate_i8_kernel<1, 1><<<agg_grid, 256, 0, stream>>>(
      G8, gsc, colidx, rs, deg, dinv, bi, Hb, emb, n);

  // conv5: MFMA projection (bf16 out) + lsm aggregate
  gemm_mfma40_kernel<<<(n + 255) / 256, 256, 0, stream>>>(Hb, W2t, dinv, G2b, n);
  agg40_lsm_kernel<<<agg_grid, 256, 0, stream>>>(G2b, colidx, rs, deg, dinv, b2, out_lsm, n);
}